// Round 9
// baseline (442.561 us; speedup 1.0000x reference)
//
#include <hip/hip_runtime.h>
#include <hip/hip_bf16.h>

// EncoderCell, bf16-MFMA, round 13.
//   attn_mfma: round-12 2-barrier pipeline +
//     (a) Ps now [128][64] XOR-granule-swizzled (same scheme as Ks/Vs):
//         P writes <=2-way banks (free), P b128 reads conflict-free.
//         LDS 50->48 KB.
//     (b) mask prefetched 1 iter ahead into regs (mvA/mvB, 2x-unrolled
//         loop); vmcnt(6) ledger unchanged: retires mask(t)x4+V(t)+K(t).
//   gemm256:   256x256 8-phase (T2-T5): FFN1 (grid 256) + FFN2 split-K4.
//   gemm_bf16: 128x128 2-phase: QKV (vhT epilogue) + out-proj split-K2.
//   ln_res:    float4-vectorized; up to 4 partials.
// ws (MiB): [0,24) qb|zb[8,16)|xb[16,24) ; [24,30) WqkvT ; [30,32) WdT ;
//   [32,40) W1T ; [40,48) W2T ; [48,64) qh|kh ; [64,72) vhT ;
//   zd0 [48,64), zd1 [64,80) ; x [80,96) ; h1 [96,128) ;
//   FFN2 partials y {0,16,48,64} MiB.

#define SEQ 2048
#define DM  1024
#define LNEPS 1e-5f

typedef __attribute__((ext_vector_type(8))) short bf16x8;
typedef __attribute__((ext_vector_type(4))) float f32x4;

#define GAS __attribute__((address_space(1)))
#define LAS __attribute__((address_space(3)))

static __device__ __forceinline__ void gl_lds16(const unsigned short* g, unsigned short* l) {
    __builtin_amdgcn_global_load_lds((const GAS void*)g, (LAS void*)l, 16, 0, 0);
}

static __device__ __forceinline__ unsigned short f2bf(float f) {
    unsigned u = __builtin_bit_cast(unsigned, f);
    u += 0x7fffu + ((u >> 16) & 1u);   // RNE
    return (unsigned short)(u >> 16);
}

static __device__ __forceinline__ unsigned cvt_pk_bf16(float lo, float hi) {
    unsigned r;
    asm("v_cvt_pk_bf16_f32 %0, %1, %2" : "=v"(r) : "v"(lo), "v"(hi));
    return r;
}

// ------------------------------------------------------------------
// gemm256: per-z C = A(+z*sA cols) @ Bt(+z*sB cols)^T (+bias on z==0).
// BM=BN=256, BK=64, 512 thr = 8 waves (2M x 4N). 2-slot K-tile LDS ring.
// 4 quadrant-phases/tile: {stage pair -> [p0: vmcnt(2)] -> barrier ->
// ds_read -> lgkm(0) -> setprio 16xMFMA -> barrier}. XOR-chunk swizzle.
// Cf (fp32 partials): slot = zskip&&z>=2 ? z+1 : z ; base = slot*sC.
// Cb (bf16): ep==2 -> bias+relu.
// ------------------------------------------------------------------
__global__ __launch_bounds__(512) void gemm256(
    const unsigned short* __restrict__ A, const unsigned short* __restrict__ Bt,
    unsigned short* __restrict__ Cb, float* __restrict__ Cf,
    int N, int Klen, int lda, int ldb,
    size_t sA, size_t sB, size_t sC, int zskip,
    const float* __restrict__ bias, int ep, int lgn)
{
    __shared__ unsigned short Asl[2][2][128 * 64];   // [slot][half][row*64+col]
    __shared__ unsigned short Bsl[2][2][128 * 64];

    const int t = threadIdx.x, lane = t & 63, w = t >> 6;
    const int wm = w >> 2, wn = w & 3;
    const int l15 = lane & 15, l16 = lane >> 4;

    const int nwg = gridDim.x;
    const int sw = (blockIdx.x & 7) * (nwg >> 3) + (blockIdx.x >> 3);
    const int n0 = (sw & ((1 << lgn) - 1)) * 256;
    const int m0 = (sw >> lgn) * 256;

    A  += (size_t)blockIdx.z * sA;
    Bt += (size_t)blockIdx.z * sB;
    int zi = blockIdx.z; if (zskip && zi >= 2) zi++;
    const size_t cbase = (size_t)zi * sC;

    const int sr = t >> 3, sc = t & 7;
    const int gcs = (sc ^ (sr & 7)) * 8;

    f32x4 acc[8][4];
    #pragma unroll
    for (int i = 0; i < 8; i++)
        #pragma unroll
        for (int j = 0; j < 4; j++)
            acc[i][j] = (f32x4){0.f, 0.f, 0.f, 0.f};

    auto STAGEPAIR = [&](int kt, int ph) {
        const int slot = kt & 1;
        if (ph < 2) {
            #pragma unroll
            for (int p = 0; p < 2; p++)
                gl_lds16(&A[(size_t)(m0 + ph * 128 + p * 64 + sr) * lda + kt * 64 + gcs],
                         &Asl[slot][ph][p * 4096 + w * 512]);
        } else {
            const int h = ph - 2;
            #pragma unroll
            for (int p = 0; p < 2; p++)
                gl_lds16(&Bt[(size_t)(n0 + h * 128 + p * 64 + sr) * ldb + kt * 64 + gcs],
                         &Bsl[slot][h][p * 4096 + w * 512]);
        }
    };

    #pragma unroll
    for (int ph = 0; ph < 4; ph++) STAGEPAIR(0, ph);

    const int NT = Klen >> 6;
    for (int T = 0; T < NT; T++) {
        const int slot = T & 1;
        const int Tn = (T + 1 < NT) ? T + 1 : 0;

        bf16x8 afr[4][2], bfr[2][2];

        auto LOADA = [&](int MH) {
            #pragma unroll
            for (int mi = 0; mi < 4; mi++)
                #pragma unroll
                for (int kk = 0; kk < 2; kk++) {
                    const int r = MH * 64 + mi * 16 + l15;
                    afr[mi][kk] = *(const bf16x8*)
                        &Asl[slot][wm][r * 64 + (((kk * 4 + l16) ^ (r & 7)) * 8)];
                }
        };
        auto LOADB = [&](int NH) {
            #pragma unroll
            for (int ni = 0; ni < 2; ni++)
                #pragma unroll
                for (int kk = 0; kk < 2; kk++) {
                    const int r = (wn & 1) * 64 + NH * 32 + ni * 16 + l15;
                    bfr[ni][kk] = *(const bf16x8*)
                        &Bsl[slot][wn >> 1][r * 64 + (((kk * 4 + l16) ^ (r & 7)) * 8)];
                }
        };
        auto MFMA16 = [&](int MH, int NH) {
            __builtin_amdgcn_s_setprio(1);
            #pragma unroll
            for (int mi = 0; mi < 4; mi++)
                #pragma unroll
                for (int ni = 0; ni < 2; ni++) {
                    acc[MH * 4 + mi][NH * 2 + ni] = __builtin_amdgcn_mfma_f32_16x16x32_bf16(
                        afr[mi][0], bfr[ni][0], acc[MH * 4 + mi][NH * 2 + ni], 0, 0, 0);
                    acc[MH * 4 + mi][NH * 2 + ni] = __builtin_amdgcn_mfma_f32_16x16x32_bf16(
                        afr[mi][1], bfr[ni][1], acc[MH * 4 + mi][NH * 2 + ni], 0, 0, 0);
                }
            __builtin_amdgcn_s_setprio(0);
        };

        STAGEPAIR(Tn, 0);
        asm volatile("s_waitcnt vmcnt(2)" ::: "memory");
        __builtin_amdgcn_s_barrier();
        __builtin_amdgcn_sched_barrier(0);
        LOADA(0); LOADB(0);
        asm volatile("s_waitcnt lgkmcnt(0)" ::: "memory");
        __builtin_amdgcn_sched_barrier(0);
        MFMA16(0, 0);
        __builtin_amdgcn_s_barrier();

        STAGEPAIR(Tn, 1);
        __builtin_amdgcn_s_barrier();
        __builtin_amdgcn_sched_barrier(0);
        LOADB(1);
        asm volatile("s_waitcnt lgkmcnt(0)" ::: "memory");
        __builtin_amdgcn_sched_barrier(0);
        MFMA16(0, 1);
        __builtin_amdgcn_s_barrier();

        STAGEPAIR(Tn, 2);
        __builtin_amdgcn_s_barrier();
        __builtin_amdgcn_sched_barrier(0);
        LOADA(1);
        asm volatile("s_waitcnt lgkmcnt(0)" ::: "memory");
        __builtin_amdgcn_sched_barrier(0);
        MFMA16(1, 1);
        __builtin_amdgcn_s_barrier();

        STAGEPAIR(Tn, 3);
        __builtin_amdgcn_s_barrier();
        __builtin_amdgcn_sched_barrier(0);
        LOADB(0);
        asm volatile("s_waitcnt lgkmcnt(0)" ::: "memory");
        __builtin_amdgcn_sched_barrier(0);
        MFMA16(1, 0);
        __builtin_amdgcn_s_barrier();
    }

    asm volatile("s_waitcnt vmcnt(0)" ::: "memory");

    if (Cf) {
        // fp32 partial epilogue (split-K): bias only on z==0
        #pragma unroll
        for (int f = 0; f < 8; f++) {
            const int row0 = m0 + wm * 128 + (f >> 2) * 64 + (f & 3) * 16 + l16 * 4;
            #pragma unroll
            for (int g = 0; g < 4; g++) {
                const int col = n0 + wn * 64 + (g >> 1) * 32 + (g & 1) * 16 + l15;
                const float bv = (ep && blockIdx.z == 0) ? bias[col] : 0.f;
                #pragma unroll
                for (int r = 0; r < 4; r++)
                    Cf[cbase + (size_t)(row0 + r) * N + col] = acc[f][g][r] + bv;
            }
        }
        return;
    }

    #pragma unroll
    for (int f = 0; f < 8; f++) {
        const int row0 = m0 + wm * 128 + (f >> 2) * 64 + (f & 3) * 16 + l16 * 4;
        #pragma unroll
        for (int g = 0; g < 4; g++) {
            const int col = n0 + wn * 64 + (g >> 1) * 32 + (g & 1) * 16 + l15;
            const float bv = ep ? bias[col] : 0.f;
            #pragma unroll
            for (int r = 0; r < 4; r++) {
                float vv = acc[f][g][r] + bv;
                if (ep == 2) vv = fmaxf(vv, 0.f);
                Cb[(size_t)(row0 + r) * N + col] = f2bf(vv);
            }
        }
    }
}

// ------------------------------------------------------------------
// gemm_bf16: 128x128 2-phase. QKV (CbT vhT epilogue on z==2), out-proj
// split-K2. Flat grid + XCD swizzle.
// ------------------------------------------------------------------
__global__ __launch_bounds__(256) void gemm_bf16(
    const unsigned short* __restrict__ A, const unsigned short* __restrict__ Bt,
    float* __restrict__ Cf, unsigned short* __restrict__ Cb,
    unsigned short* __restrict__ CbT,
    int M, int N, int Klen, int lda, int ldb,
    size_t sA, size_t sB, size_t sC,
    const float* __restrict__ bias, int ep, int lgn)
{
    __shared__ unsigned short As[2][128 * 32];
    __shared__ unsigned short Bs[2][128 * 32];

    const int t = threadIdx.x, lane = t & 63, w = t >> 6;
    const int wm = w >> 1, wn = w & 1;

    const int nwg = gridDim.x;
    const int sw = (blockIdx.x & 7) * (nwg >> 3) + (blockIdx.x >> 3);
    const int n0 = (sw & ((1 << lgn) - 1)) * 128;
    const int m0 = (sw >> lgn) * 128;

    A  += (size_t)blockIdx.z * sA;
    Bt += (size_t)blockIdx.z * sB;
    const size_t cbase = (size_t)blockIdx.z * sC;
    const int l15 = lane & 15, l16 = lane >> 4;
    const int ar = lane >> 2, ac = (lane & 3) * 8;

    f32x4 acc[4][4];
    #pragma unroll
    for (int i = 0; i < 4; i++)
        #pragma unroll
        for (int j = 0; j < 4; j++)
            acc[i][j] = (f32x4){0.f, 0.f, 0.f, 0.f};

    auto stage = [&](int buf, int k0) {
        #pragma unroll
        for (int i = 0; i < 2; i++) {
            const int rg = w * 2 + i;
            gl_lds16(&A [(size_t)(m0 + rg * 16 + ar) * lda + k0 + ac], &As[buf][rg * 512]);
            gl_lds16(&Bt[(size_t)(n0 + rg * 16 + ar) * ldb + k0 + ac], &Bs[buf][rg * 512]);
        }
    };
    auto compute = [&](int buf) {
        bf16x8 af[4], bfr[4];
        #pragma unroll
        for (int i = 0; i < 4; i++) {
            af[i]  = *(const bf16x8*)&As[buf][(wm * 64 + i * 16 + l15) * 32 + l16 * 8];
            bfr[i] = *(const bf16x8*)&Bs[buf][(wn * 64 + i * 16 + l15) * 32 + l16 * 8];
        }
        #pragma unroll
        for (int mi = 0; mi < 4; mi++)
            #pragma unroll
            for (int ni = 0; ni < 4; ni++)
                acc[mi][ni] = __builtin_amdgcn_mfma_f32_16x16x32_bf16(
                    af[mi], bfr[ni], acc[mi][ni], 0, 0, 0);
    };

    stage(0, 0);
    __syncthreads();
    int k0 = 0;
    for (; k0 + 32 < Klen; k0 += 32) {
        const int cur = (k0 >> 5) & 1;
        stage(cur ^ 1, k0 + 32);
        compute(cur);
        __syncthreads();
    }
    compute((k0 >> 5) & 1);

    if (CbT && blockIdx.z == 2) {
        // write V-projection directly transposed: vhT[(b*16+h)*64+d][s]
        #pragma unroll
        for (int ni = 0; ni < 4; ni++) {
            const int col = n0 + wn * 64 + ni * 16 + l15;   // h*64 + d
            const int hh = col >> 6, d = col & 63;
            #pragma unroll
            for (int mi = 0; mi < 4; mi++) {
                const int row = m0 + wm * 64 + mi * 16 + l16 * 4;  // b*2048 + s
                const int bb = row >> 11, s = row & 2047;
                ushort4 o;
                o.x = f2bf(acc[mi][ni][0]); o.y = f2bf(acc[mi][ni][1]);
                o.z = f2bf(acc[mi][ni][2]); o.w = f2bf(acc[mi][ni][3]);
                *(ushort4*)&CbT[((size_t)((bb * 16 + hh) * 64 + d)) * SEQ + s] = o;
            }
        }
        return;
    }

    #pragma unroll
    for (int ni = 0; ni < 4; ni++) {
        const int col = n0 + wn * 64 + ni * 16 + l15;
        const float bv = (ep && blockIdx.z == 0) ? bias[col] : 0.f;
        #pragma unroll
        for (int mi = 0; mi < 4; mi++) {
            #pragma unroll
            for (int r = 0; r < 4; r++) {
                const int row = m0 + wm * 64 + mi * 16 + l16 * 4 + r;
                float vv = acc[mi][ni][r] + bv;
                if (ep == 2) vv = fmaxf(vv, 0.f);
                if (Cf) Cf[cbase + (size_t)row * N + col] = vv;
                else    Cb[cbase + (size_t)row * N + col] = f2bf(vv);
            }
        }
    }
}

// ------------------------------------------------------------------
// Flash attention, S^T formulation. 8 waves / 128 q-rows per block.
// Round 13: Ps [128][64] XOR-granule-swizzled (P writes 2-way-free, P b128
// reads conflict-free); mask prefetched 1 iter ahead in regs (mvA/mvB,
// 2x-unrolled loop). 2 barriers/iter; K,V double-buffered.
// Ledger (per wave, issue order): entry outstanding = {mask(t)x4,V(t),K(t)};
//   issue mask(t+1)x4, V(t+1), K(t+1) -> 12; vmcnt(6) retires the 6 oldest
//   = mask(t)x4 + V(t) + K(t). Prefetch pair stays in flight. Never 0.
// ------------------------------------------------------------------
__global__ __launch_bounds__(512) void attn_mfma(
    const unsigned short* __restrict__ qh, const unsigned short* __restrict__ kh,
    const unsigned short* __restrict__ vhT, const float* __restrict__ mask,
    unsigned short* __restrict__ z)
{
    __shared__ unsigned short Ks[2][64 * 64];   // swizzled [key][d], dbuf
    __shared__ unsigned short Vs[2][64 * 64];   // swizzled [d][key], dbuf
    __shared__ unsigned short Ps[128 * 64];     // [q][key] XOR-granule swizzled;
                                                // Q staging in prologue

    const int t = threadIdx.x, lane = t & 63, w = t >> 6;   // w 0..7
    const int bid = blockIdx.x;
    const int qt = bid >> 5, h = bid & 15, b = (bid >> 4) & 1;
    const int q0 = qt * 128, qr = w * 16;
    const int l15 = lane & 15, l16 = lane >> 4;

    const int lr = lane >> 3;
    const int gc = ((lane & 7) ^ lr) * 8;     // swizzled source chunk (shorts)

    const size_t qbase = (size_t)(b * SEQ + q0) * DM + h * 64;
    const size_t kbase = (size_t)(b * SEQ) * DM + h * 64;
    const size_t vbase = (size_t)((b * 16 + h) * 64) * SEQ;

    const float* mrow = mask + (size_t)(q0 + qr + l15) * SEQ;

    // prologue: mask(0) -> regs; Q (128 rows) -> Ps; K0 -> Ks[0]; V0 -> Vs[0]
    float4 mvA[4], mvB[4];
    #pragma unroll
    for (int ki = 0; ki < 4; ki++)
        mvA[ki] = *(const float4*)&mrow[ki * 16 + l16 * 4];
    #pragma unroll
    for (int i = 0; i < 2; i++) {
        const int rg = w * 2 + i;
        gl_lds16(&qh[qbase + (size_t)(rg * 8 + lr) * DM + gc], &Ps[rg * 512]);
    }
    gl_lds16(&kh [kbase + (size_t)(w * 8 + lr) * DM + gc],  &Ks[0][w * 512]);
    gl_lds16(&vhT[vbase + (size_t)(w * 8 + lr) * SEQ + gc], &Vs[0][w * 512]);
    __syncthreads();   // drains vmcnt(0): mask0 regs, Q, K0, V0 resident

    const int sw0 = ((l16    ) ^ (l15 & 7)) * 8;
    const int sw1 = ((l16 + 4) ^ (l15 & 7)) * 8;
    const bf16x8 bQ0 = *(const bf16x8*)&Ps[(qr + l15) * 64 + sw0];
    const bf16x8 bQ1 = *(const bf16x8*)&Ps[(qr + l15) * 64 + sw1];
    __syncthreads();   // everyone consumed Q; Ps free for P

    // P-write swizzled offset: granule (ki*2 + (l16>>1)) ^ (l15&7), half l16&1
    const int pw_half = (l16 & 1) * 4;
    const int pw_x7   = l15 & 7;

    float m_i = -1e30f, l_i = 0.f;
    f32x4 o4[4];
    #pragma unroll
    for (int mi = 0; mi < 4; mi++) o4[mi] = (f32x4){0.f, 0.f, 0.f, 0.f};

    auto ITER = [&](int kt, float4 (&mvU)[4], float4 (&mvN)[4]) {
        const int kn = ((kt + 1) & (SEQ / 64 - 1)) * 64;   // wrap: last iter redundant
        const int cur = kt & 1, nxt = cur ^ 1;

        // (A) top barrier: all waves done with Ks[nxt]/Vs[nxt] from t-1.
        __builtin_amdgcn_s_barrier();

        // prefetch mask(t+1) -> mvN, then V(t+1),K(t+1) (order pinned)
        #pragma unroll
        for (int ki = 0; ki < 4; ki++)
            mvN[ki] = *(const float4*)&mrow[kn + ki * 16 + l16 * 4];
        __builtin_amdgcn_sched_barrier(0);
        gl_lds16(&vhT[vbase + (size_t)(w * 8 + lr) * SEQ + kn + gc], &Vs[nxt][w * 512]);
        gl_lds16(&kh [kbase + (size_t)(kn + w * 8 + lr) * DM + gc],  &Ks[nxt][w * 512]);

        // retire the 6 oldest = mask(t)x4 + V(t) + K(t)
        asm volatile("s_waitcnt vmcnt(6)" ::: "memory");
        __builtin_amdgcn_s_barrier();        // (B) tile t fully staged by all waves
        __builtin_amdgcn_sched_barrier(0);

        // S^T = K . Q^T : row=key, col=q
        f32x4 s4[4];
        __builtin_amdgcn_s_setprio(1);
        #pragma unroll
        for (int ki = 0; ki < 4; ki++) {
            const int r = ki * 16 + l15;
            const bf16x8 aK0 = *(const bf16x8*)&Ks[cur][r * 64 + sw0];
            const bf16x8 aK1 = *(const bf16x8*)&Ks[cur][r * 64 + sw1];
            f32x4 a0 = (f32x4){0.f, 0.f, 0.f, 0.f};
            a0 = __builtin_amdgcn_mfma_f32_16x16x32_bf16(aK0, bQ0, a0, 0, 0, 0);
            s4[ki] = __builtin_amdgcn_mfma_f32_16x16x32_bf16(aK1, bQ1, a0, 0, 0, 0);
        }
        __builtin_amdgcn_s_setprio(0);

        float sv[16];
        #pragma unroll
        for (int ki = 0; ki < 4; ki++) {
            sv[ki * 4 + 0] = s4[ki][0] * 0.125f + mvU[ki].x;
            sv[ki * 4 + 1] = s4[ki][1] * 0.125f + mvU[ki].y;
            sv[ki * 4 + 2] = s4[ki][2] * 0.125f + mvU[ki].z;
            sv[ki * 4 + 3] = s4[ki][3] * 0.125f + mvU[ki].w;
        }

        float rm = fmaxf(sv[0], sv[1]);
        #pragma unroll
        for (int i = 2; i < 16; i += 2) rm = fmaxf(fmaxf(rm, sv[i]), sv[i + 1]);
        rm = fmaxf(rm, __shfl_xor(rm, 16));
        rm = fmaxf(rm, __shfl_xor(rm, 32));

        const bool skip = __all(rm <= m_i + 8.f);
        float mnew = m_i, alpha = 1.f;
        if (!skip) { mnew = fmaxf(m_i, rm); alpha = __expf(m_i - mnew); }

        float ps = 0.f;
        #pragma unroll
        for (int ki = 0; ki < 4; ki++) {
            const float p0 = __expf(sv[ki * 4 + 0] - mnew);
            const float p1 = __expf(sv[ki * 4 + 1] - mnew);
            const float p2 = __expf(sv[ki * 4 + 2] - mnew);
            const float p3 = __expf(sv[ki * 4 + 3] - mnew);
            ps += (p0 + p1) + (p2 + p3);
            uint2 pk;
            pk.x = cvt_pk_bf16(p0, p1);
            pk.y = cvt_pk_bf16(p2, p3);
            // swizzled P write: granule (ki*2+(l16>>1)) ^ (l15&7), half l16&1
            *(uint2*)&Ps[(qr + l15) * 64 +
                         (((ki * 2 + (l16 >> 1)) ^ pw_x7) * 8 + pw_half)] = pk;
        }
        ps += __shfl_xor(ps, 16);
        ps += __shfl_xor(ps, 32);
        if (!skip) {
            m_i = mnew;
            l_i = l_i * alpha + ps;
            #pragma unroll
            for (int mi = 0; mi < 4; mi++)
                #pragma unroll
                for (int r = 0; r < 4; r++) o4[mi][r] *= alpha;
        } else {
            l_i += ps;
        }

        // Ps wave-private: own ds_writes just need to land before own ds_reads.
        asm volatile("s_waitcnt lgkmcnt(0)" ::: "memory");
        __builtin_amdgcn_sched_barrier(0);

        const bf16x8 bP0 = *(const bf16x8*)&Ps[(qr + l15) * 64 + sw0];
        const bf16x8 bP1 = *(const bf16x8*)&Ps[(qr + l15) * 64 + sw1];
        __builtin_amdgcn_s_setprio(1);
        #pragma unroll
        for (int mi = 0; mi < 4; mi++) {
            const int r = mi * 16 + l15;
            const bf16x8 aV0 = *(const bf16x8*)&Vs[cur][r * 64 + sw0];
            const bf16x8 aV1 = *(const bf16x8*)&Vs[cur][r * 64 + sw1];
            o4[mi] = __builtin_amdgcn_mfma_f32_16x16x32_bf16(aV0, bP0, o4[mi], 0, 0, 0);
            o4[mi] = __builtin_amdgcn_mfma_f32_16x16x32_bf16(aV1, bP1, o4[mi], 0, 0, 0);
        }
        __builtin_amdgcn_s_setprio(0);
    };

    for (int kt2 = 0; kt2 < SEQ / 64; kt2 += 2) {
        ITER(kt2,     mvA, mvB);
        ITER(kt2 + 1, mvB, mvA);
    }

    asm volatile("s_waitcnt vmcnt(0)" ::: "memory");

    const float inv = 1.f / l_i;
    #pragma unroll
    for (int mi = 0; mi < 4; mi++) {
        const float a0 = o4[mi][0] * inv, a1 = o4[mi][1] * inv;
        const float a2 = o4[mi][2] * inv, a3 = o4[mi][3] * inv;
        uint2 ov;
        ov.x = cvt_pk_bf16(a0, a1);
        ov.y = cvt_pk_bf16(a2, a3);
        *(uint2*)&z[(size_t)(b * SEQ + q0 + qr + l15) * DM + h * 64 + mi * 16 + l16 * 4] = ov;
    }
}

// ------------------------------------------------------------------
// prep: one launch for all input prep. grid (64,16,9).
// ------------------------------------------------------------------
__global__ __launch_bounds__(256) void prep(
    const float* __restrict__ q, const float* __restrict__ k, const float* __restrict__ v,
    unsigned short* __restrict__ qb,
    const float* __restrict__ Wq, const float* __restrict__ Wk,
    const float* __restrict__ Wv, const float* __restrict__ Wd,
    const float* __restrict__ W1, const float* __restrict__ W2,
    unsigned short* __restrict__ Wqt, unsigned short* __restrict__ Wdt,
    unsigned short* __restrict__ W1t, unsigned short* __restrict__ W2t)
{
    const int z = blockIdx.z, t = threadIdx.x;
    const int flat = blockIdx.y * 64 + blockIdx.x;

    if (z < 3) {
        const float* src = z == 0 ? q : (z == 1 ? k : v);
        unsigned short* dst = qb + (size_t)z * ((size_t)SEQ * 2 * DM);
        const size_t base = (size_t)flat * 4096 + t * 4;
        #pragma unroll
        for (int i = 0; i < 4; i++) {
            const float4 w4 = *(const float4*)&src[base + i * 1024];
            ushort4 o; o.x = f2bf(w4.x); o.y = f2bf(w4.y); o.z = f2bf(w4.z); o.w = f2bf(w4.w);
            *(ushort4*)&dst[base + i * 1024] = o;
        }
        return;
    }

    __shared__ float ts[64][65];
    const float* W; unsigned short* Wt; int K, N, n0, k0;
    if (z < 7) {
        if (flat >= 256) return;
        W  = z == 3 ? Wq : z == 4 ? Wk : (z == 5 ? Wv : Wd);
        Wt = z == 3 ? Wqt : z == 4 ? Wqt + 1024 * 1024
           : z == 5 ? Wqt + 2 * 1024 * 1024 : Wdt;
        K = 1024; N = 1024;
        n0 = (flat & 15) * 64; k0 = (flat >> 4) * 64;
    } else if (z == 7) {
        W = W1; Wt = W1t; K = 1024; N = 4096;
        n0 = blockIdx.x * 64; k0 = blockIdx.y * 64;
    } else {
        W = W2; Wt = W2t; K = 4096; N = 1024;
        n0 = (flat & 15) * 64; k0 = (flat >> 4) * 64;
    }

    const int r = t >> 4, c4 = (t & 15) * 4;
    #pragma unroll
    for (int i = 0; i < 4; i++) {
        const float4 v4 = *(const float4*)&W[(size_t)(k0 + r + i * 16) * N + n0 + c4];
        ts[r + i * 16][c4 + 0] = v4.x; ts[r + i * 16][c4 + 1] = v4.y;
        ts[r + i * 16][c4 + 2] = v4.z; ts[r + i * 16][c4 + 3] = v4.w;
    }
    __syncthreads();
    #pragma unroll
    for (int i = 0; i < 4; i++) {
        const int n = r + i * 16;
        ushort4 o;
        o.x = f2bf(ts[c4 + 0][n]); o.y = f2bf(ts[c4 + 1][n]);
        o.z = f2bf(ts[c4 + 2][n]); o.w = f2bf(ts[c4 + 3][n]);
        *(ushort4*)&Wt[(size_t)(n0 + n) * K + k0 + c4] = o;
    }
}

// ------------------------------------------------------------------
// LN + residual, float4-vectorized; up to 4 partial inputs (nullable).
// mode 0: out = LN(sum)*g+be + r (+bf16 copy) ; mode 1: out = LN(sum+r)*g+be
// ------------------------------------------------------------------
__global__ __launch_bounds__(256) void ln_res(
    const float* __restrict__ a, const float* __restrict__ a2,
    const float* __restrict__ a3, const float* __restrict__ a4,
    const float* __restrict__ r,
    const float* __restrict__ g, const float* __restrict__ be,
    float* __restrict__ out, unsigned short* __restrict__ outb, int mode)
{
    __shared__ float redls[8];
    const int row = blockIdx.x, t = threadIdx.x;
    const size_t base = (size_t)row * DM;
    const int c = t * 4;

    float4 va = *(const float4*)&a[base + c];
    if (a2) { const float4 v2 = *(const float4*)&a2[base + c];
              va.x += v2.x; va.y += v2.y; va.z += v2.z; va.w += v2.w; }
    if (a3) { const float4 v3 = *(const float4*)&a3[base + c];
              va.x += v3.x; va.y += v3.y; va.z += v3.z; va.w += v3.w; }
    if (a4) { const float4 v4 = *(const float4*)&a4[base + c];
              va.x += v4.x; va.y += v4.y; va.z += v4.z; va.w += v4.w; }
    float4 vr;
    if (mode == 1) { vr = *(const float4*)&r[base + c];
                     va.x += vr.x; va.y += vr.y; va.z += vr.z; va.w += vr.w; }

    float s  = (va.x + va.y) + (va.z + va.w);
    float sq = (va.x * va.x + va.y * va.y) + (va.z * va.z + va.w * va.w);
    #pragma unroll
    for (int off = 32; off > 0; off >>= 1) { s += __shfl_down(s, off); sq += __shfl_down(sq, off); }
    if ((t & 63) == 0) { redls[t >> 6] = s; redls[4 + (t >> 6)] = sq; }
    __syncthreads();
    s  = redls[0] + redls[1] + redls[2] + redls[3];
    sq = redls[4] + redls[5] + redls[6] + redls[7];

    const float mu  = s * (1.f / 1024.f);
    const float var = sq * (1.f / 1024.f) - mu * mu;
    const float rs  = rsqrtf(var + LNEPS);

    const float4 vg = *(const float4*)&g[c];
    const float4 vb = *(const float4*)&be[c];
    float4 y;
    y.x = (va.x - mu) * rs * vg.x + vb.x;
    y.y = (va.y - mu) * rs * vg.y + vb.y;
    y.z = (va.z - mu) * rs * vg.z + vb.z;
    y.w = (va.w - mu) * rs * vg.w + vb.w;
    if (mode == 0) {
        vr = *(const float4*)&r[base + c];
        y.x += vr.x; y.y += vr.y; y.z += vr.z; y.w += vr.w;
    }
    *(float4*)&out[base + c] = y;
    if (outb) {
        ushort4 o;
        o.x = f2bf(y.x); o.y = f2bf(y.y); o.z = f2bf(y.z); o.w = f2bf(y.w);
        *(ushort4*)&outb[base + c] = o;
    }
}

// ------------------------------------------------------------------
extern "C" void kernel_launch(void* const* d_in, const int* in_sizes, int n_in,
                              void* d_out, int out_size, void* d_ws, size_t ws_size,
                              hipStream_t stream)
{
    const float* q    = (const float*)d_in[0];
    const float* k    = (const float*)d_in[1];
    const float* v    = (const float*)d_in[2];
    const float* mask = (const float*)d_in[4];
    const float* Wq   = (const float*)d_in[5];
    const float* Wk   = (const float*)d_in[6];
    const float* Wv   = (const float*)d_in[7];
    const float* Wd   = (const float*)d_in[8];
    const float* W1   = (const float*)d_in[9];
    const float* b1   = (const float*)d_in[10];
    const float* W2   = (const float*)d_in[11];
    const float* b2   = (const float*)d_in[12];
    const float* g1   = (const float*)d_in[13];
    const float* be1  = (const float*)d_in[14];
    const float* g2   = (const float*)d_in[15];
    const float* be2  = (const float*)d_in[16];
    float* out = (float*)d_out;

    char* WS = (char*)d_ws;
    const size_t MiB = 1u << 20;
    const size_t ND  = (size_t)4096 * 1024;

    unsigned short* qb  = (unsigned short*)(WS + 0);          // 24 MiB qb|kb|vb
    unsigned short* zb  = (unsigned short*)(WS + 8 * MiB);    //  8 MiB (reuse)
    unsigned short* xb  = (unsigned short*)(WS + 16 * MiB);   //  8 MiB (reuse)
    unsigned short* Wqt = (unsigned short*)(WS + 24 * MiB);   //  6 MiB WqT|WkT|WvT
    unsigned short* Wdt = (unsigned short*)(WS + 30 * MiB);   //  2 MiB
    unsigned short* W1t = (unsigned short*)(WS + 32 * MiB);   //  8 MiB
    unsigned short* W2t = (unsigned short*)(WS + 40 * MiB);   //  8 MiB
    unsigned short* qh  = (unsigned short*)(WS + 48 * MiB);   // 16 MiB qh|kh
    unsigned short* vhT = (unsigned short*)(WS + 64 * MiB);   //  8 MiB (direct)
    float*          zd0 = (float*)(WS + 48 * MiB);            // 16 MiB (reuse qh|kh)
    float*          zd1 = (float*)(WS + 64 * MiB);            // 16 MiB (reuse vhT+)
    float*          x   = (float*)(WS + 80 * MiB);            // 16 MiB
    unsigned short* h1  = (unsigned short*)(WS + 96 * MiB);   // 32 MiB
    // FFN2 split-K4 partials, slots {0,1,3,4} x 16 MiB (slot 2 = live W1t/W2t)
    float*          y0  = (float*)(WS + 0);
    float*          y1  = (float*)(WS + 16 * MiB);
    float*          y2  = (float*)(WS + 48 * MiB);
    float*          y3  = (float*)(WS + 64 * MiB);

    unsigned short* kh = qh + ND;

    const dim3 blk(256);

    prep<<<dim3(64, 16, 9), blk, 0, stream>>>(q, k, v, qb, Wq, Wk, Wv, Wd, W1, W2,
                                              Wqt, Wdt, W1t, W2t);

    // QKV projections via 2-phase gemm_bf16 (768 blocks; z==2 writes vhT)
    gemm_bf16<<<dim3(256, 1, 3), blk, 0, stream>>>(qb, Wqt, nullptr, qh, vhT,
        4096, 1024, 1024, 1024, 1024, ND, (size_t)1024 * 1024, ND, nullptr, 0, 3);

    attn_mfma<<<dim3(512), dim3(512), 0, stream>>>(qh, kh, vhT, mask, zb);

    // out-proj, split-K x2 -> zd0/zd1
    gemm_bf16<<<dim3(256, 1, 2), blk, 0, stream>>>(zb, Wdt, zd0, nullptr, nullptr,
        4096, 1024, 512, 1024, 1024, 512, 512, ND, nullptr, 0, 3);

    // LN1: x = LN(zd0+zd1) + q
    ln_res<<<dim3(4096), blk, 0, stream>>>(zd0, zd1, nullptr, nullptr, q,
                                           g1, be1, x, xb, 0);

    // FFN1 via gemm256 (grid 256 = 1 block/CU), bf16 out + bias + relu
    gemm256<<<dim3(256, 1, 1), dim3(512), 0, stream>>>(xb, W1t, h1, nullptr,
        4096, 1024, 1024, 1024, 0, 0, 0, 0, b1, 2, 4);

    // FFN2 via gemm256 split-K4 (grid 64x4 = 256 wg = 1 block/CU), fp32
    // partials to slots {0,1,3,4} x 16 MiB; bias b2 on z==0
    gemm256<<<dim3(64, 1, 4), dim3(512), 0, stream>>>(h1, W2t, nullptr, (float*)WS,
        1024, 1024, 4096, 4096, 1024, 1024, (size_t)4 * 1024 * 1024, 1, b2, 1, 2);

    // LN2: out = LN(y0+y1+y2+y3+x)
    ln_res<<<dim3(4096), blk, 0, stream>>>(y0, y1, y2, y3, x, g2, be2, out, nullptr, 1);
}

// Round 10
// 428.738 us; speedup vs baseline: 1.0322x; 1.0322x over previous
//
#include <hip/hip_runtime.h>
#include <hip/hip_bf16.h>

// EncoderCell, bf16-MFMA, round 14.
//   attn_mfma: round-12 2-barrier pipeline (in-loop mask loads, plain loop)
//              + round-13's Ps [128][64] XOR-granule swizzle (kept: bank
//              conflicts 3.14M -> 2.10M measured). Mask reg-prefetch REVERTED
//              (round-9 post-mortem: +16 VGPR / 2x code size cost > benefit;
//              mask latency already hidden under QK MFMA phase).
//   gemm256:   256x256 8-phase (T2-T5): FFN1 (grid 256) + FFN2 split-K4.
//   gemm_bf16: 128x128 2-phase: QKV (vhT epilogue) + out-proj split-K2.
//   ln_res:    float4-vectorized; up to 4 partials.
// ws (MiB): [0,24) qb|zb[8,16)|xb[16,24) ; [24,30) WqkvT ; [30,32) WdT ;
//   [32,40) W1T ; [40,48) W2T ; [48,64) qh|kh ; [64,72) vhT ;
//   zd0 [48,64), zd1 [64,80) ; x [80,96) ; h1 [96,128) ;
//   FFN2 partials y {0,16,48,64} MiB.

#define SEQ 2048
#define DM  1024
#define LNEPS 1e-5f

typedef __attribute__((ext_vector_type(8))) short bf16x8;
typedef __attribute__((ext_vector_type(4))) float f32x4;

#define GAS __attribute__((address_space(1)))
#define LAS __attribute__((address_space(3)))

static __device__ __forceinline__ void gl_lds16(const unsigned short* g, unsigned short* l) {
    __builtin_amdgcn_global_load_lds((const GAS void*)g, (LAS void*)l, 16, 0, 0);
}

static __device__ __forceinline__ unsigned short f2bf(float f) {
    unsigned u = __builtin_bit_cast(unsigned, f);
    u += 0x7fffu + ((u >> 16) & 1u);   // RNE
    return (unsigned short)(u >> 16);
}

static __device__ __forceinline__ unsigned cvt_pk_bf16(float lo, float hi) {
    unsigned r;
    asm("v_cvt_pk_bf16_f32 %0, %1, %2" : "=v"(r) : "v"(lo), "v"(hi));
    return r;
}

// ------------------------------------------------------------------
// gemm256: per-z C = A(+z*sA cols) @ Bt(+z*sB cols)^T (+bias on z==0).
// BM=BN=256, BK=64, 512 thr = 8 waves (2M x 4N). 2-slot K-tile LDS ring.
// 4 quadrant-phases/tile: {stage pair -> [p0: vmcnt(2)] -> barrier ->
// ds_read -> lgkm(0) -> setprio 16xMFMA -> barrier}. XOR-chunk swizzle.
// Cf (fp32 partials): slot = zskip&&z>=2 ? z+1 : z ; base = slot*sC.
// Cb (bf16): ep==2 -> bias+relu.
// ------------------------------------------------------------------
__global__ __launch_bounds__(512) void gemm256(
    const unsigned short* __restrict__ A, const unsigned short* __restrict__ Bt,
    unsigned short* __restrict__ Cb, float* __restrict__ Cf,
    int N, int Klen, int lda, int ldb,
    size_t sA, size_t sB, size_t sC, int zskip,
    const float* __restrict__ bias, int ep, int lgn)
{
    __shared__ unsigned short Asl[2][2][128 * 64];   // [slot][half][row*64+col]
    __shared__ unsigned short Bsl[2][2][128 * 64];

    const int t = threadIdx.x, lane = t & 63, w = t >> 6;
    const int wm = w >> 2, wn = w & 3;
    const int l15 = lane & 15, l16 = lane >> 4;

    const int nwg = gridDim.x;
    const int sw = (blockIdx.x & 7) * (nwg >> 3) + (blockIdx.x >> 3);
    const int n0 = (sw & ((1 << lgn) - 1)) * 256;
    const int m0 = (sw >> lgn) * 256;

    A  += (size_t)blockIdx.z * sA;
    Bt += (size_t)blockIdx.z * sB;
    int zi = blockIdx.z; if (zskip && zi >= 2) zi++;
    const size_t cbase = (size_t)zi * sC;

    const int sr = t >> 3, sc = t & 7;
    const int gcs = (sc ^ (sr & 7)) * 8;

    f32x4 acc[8][4];
    #pragma unroll
    for (int i = 0; i < 8; i++)
        #pragma unroll
        for (int j = 0; j < 4; j++)
            acc[i][j] = (f32x4){0.f, 0.f, 0.f, 0.f};

    auto STAGEPAIR = [&](int kt, int ph) {
        const int slot = kt & 1;
        if (ph < 2) {
            #pragma unroll
            for (int p = 0; p < 2; p++)
                gl_lds16(&A[(size_t)(m0 + ph * 128 + p * 64 + sr) * lda + kt * 64 + gcs],
                         &Asl[slot][ph][p * 4096 + w * 512]);
        } else {
            const int h = ph - 2;
            #pragma unroll
            for (int p = 0; p < 2; p++)
                gl_lds16(&Bt[(size_t)(n0 + h * 128 + p * 64 + sr) * ldb + kt * 64 + gcs],
                         &Bsl[slot][h][p * 4096 + w * 512]);
        }
    };

    #pragma unroll
    for (int ph = 0; ph < 4; ph++) STAGEPAIR(0, ph);

    const int NT = Klen >> 6;
    for (int T = 0; T < NT; T++) {
        const int slot = T & 1;
        const int Tn = (T + 1 < NT) ? T + 1 : 0;

        bf16x8 afr[4][2], bfr[2][2];

        auto LOADA = [&](int MH) {
            #pragma unroll
            for (int mi = 0; mi < 4; mi++)
                #pragma unroll
                for (int kk = 0; kk < 2; kk++) {
                    const int r = MH * 64 + mi * 16 + l15;
                    afr[mi][kk] = *(const bf16x8*)
                        &Asl[slot][wm][r * 64 + (((kk * 4 + l16) ^ (r & 7)) * 8)];
                }
        };
        auto LOADB = [&](int NH) {
            #pragma unroll
            for (int ni = 0; ni < 2; ni++)
                #pragma unroll
                for (int kk = 0; kk < 2; kk++) {
                    const int r = (wn & 1) * 64 + NH * 32 + ni * 16 + l15;
                    bfr[ni][kk] = *(const bf16x8*)
                        &Bsl[slot][wn >> 1][r * 64 + (((kk * 4 + l16) ^ (r & 7)) * 8)];
                }
        };
        auto MFMA16 = [&](int MH, int NH) {
            __builtin_amdgcn_s_setprio(1);
            #pragma unroll
            for (int mi = 0; mi < 4; mi++)
                #pragma unroll
                for (int ni = 0; ni < 2; ni++) {
                    acc[MH * 4 + mi][NH * 2 + ni] = __builtin_amdgcn_mfma_f32_16x16x32_bf16(
                        afr[mi][0], bfr[ni][0], acc[MH * 4 + mi][NH * 2 + ni], 0, 0, 0);
                    acc[MH * 4 + mi][NH * 2 + ni] = __builtin_amdgcn_mfma_f32_16x16x32_bf16(
                        afr[mi][1], bfr[ni][1], acc[MH * 4 + mi][NH * 2 + ni], 0, 0, 0);
                }
            __builtin_amdgcn_s_setprio(0);
        };

        STAGEPAIR(Tn, 0);
        asm volatile("s_waitcnt vmcnt(2)" ::: "memory");
        __builtin_amdgcn_s_barrier();
        __builtin_amdgcn_sched_barrier(0);
        LOADA(0); LOADB(0);
        asm volatile("s_waitcnt lgkmcnt(0)" ::: "memory");
        __builtin_amdgcn_sched_barrier(0);
        MFMA16(0, 0);
        __builtin_amdgcn_s_barrier();

        STAGEPAIR(Tn, 1);
        __builtin_amdgcn_s_barrier();
        __builtin_amdgcn_sched_barrier(0);
        LOADB(1);
        asm volatile("s_waitcnt lgkmcnt(0)" ::: "memory");
        __builtin_amdgcn_sched_barrier(0);
        MFMA16(0, 1);
        __builtin_amdgcn_s_barrier();

        STAGEPAIR(Tn, 2);
        __builtin_amdgcn_s_barrier();
        __builtin_amdgcn_sched_barrier(0);
        LOADA(1);
        asm volatile("s_waitcnt lgkmcnt(0)" ::: "memory");
        __builtin_amdgcn_sched_barrier(0);
        MFMA16(1, 1);
        __builtin_amdgcn_s_barrier();

        STAGEPAIR(Tn, 3);
        __builtin_amdgcn_s_barrier();
        __builtin_amdgcn_sched_barrier(0);
        LOADB(0);
        asm volatile("s_waitcnt lgkmcnt(0)" ::: "memory");
        __builtin_amdgcn_sched_barrier(0);
        MFMA16(1, 0);
        __builtin_amdgcn_s_barrier();
    }

    asm volatile("s_waitcnt vmcnt(0)" ::: "memory");

    if (Cf) {
        // fp32 partial epilogue (split-K): bias only on z==0
        #pragma unroll
        for (int f = 0; f < 8; f++) {
            const int row0 = m0 + wm * 128 + (f >> 2) * 64 + (f & 3) * 16 + l16 * 4;
            #pragma unroll
            for (int g = 0; g < 4; g++) {
                const int col = n0 + wn * 64 + (g >> 1) * 32 + (g & 1) * 16 + l15;
                const float bv = (ep && blockIdx.z == 0) ? bias[col] : 0.f;
                #pragma unroll
                for (int r = 0; r < 4; r++)
                    Cf[cbase + (size_t)(row0 + r) * N + col] = acc[f][g][r] + bv;
            }
        }
        return;
    }

    #pragma unroll
    for (int f = 0; f < 8; f++) {
        const int row0 = m0 + wm * 128 + (f >> 2) * 64 + (f & 3) * 16 + l16 * 4;
        #pragma unroll
        for (int g = 0; g < 4; g++) {
            const int col = n0 + wn * 64 + (g >> 1) * 32 + (g & 1) * 16 + l15;
            const float bv = ep ? bias[col] : 0.f;
            #pragma unroll
            for (int r = 0; r < 4; r++) {
                float vv = acc[f][g][r] + bv;
                if (ep == 2) vv = fmaxf(vv, 0.f);
                Cb[(size_t)(row0 + r) * N + col] = f2bf(vv);
            }
        }
    }
}

// ------------------------------------------------------------------
// gemm_bf16: 128x128 2-phase. QKV (CbT vhT epilogue on z==2), out-proj
// split-K2. Flat grid + XCD swizzle.
// ------------------------------------------------------------------
__global__ __launch_bounds__(256) void gemm_bf16(
    const unsigned short* __restrict__ A, const unsigned short* __restrict__ Bt,
    float* __restrict__ Cf, unsigned short* __restrict__ Cb,
    unsigned short* __restrict__ CbT,
    int M, int N, int Klen, int lda, int ldb,
    size_t sA, size_t sB, size_t sC,
    const float* __restrict__ bias, int ep, int lgn)
{
    __shared__ unsigned short As[2][128 * 32];
    __shared__ unsigned short Bs[2][128 * 32];

    const int t = threadIdx.x, lane = t & 63, w = t >> 6;
    const int wm = w >> 1, wn = w & 1;

    const int nwg = gridDim.x;
    const int sw = (blockIdx.x & 7) * (nwg >> 3) + (blockIdx.x >> 3);
    const int n0 = (sw & ((1 << lgn) - 1)) * 128;
    const int m0 = (sw >> lgn) * 128;

    A  += (size_t)blockIdx.z * sA;
    Bt += (size_t)blockIdx.z * sB;
    const size_t cbase = (size_t)blockIdx.z * sC;
    const int l15 = lane & 15, l16 = lane >> 4;
    const int ar = lane >> 2, ac = (lane & 3) * 8;

    f32x4 acc[4][4];
    #pragma unroll
    for (int i = 0; i < 4; i++)
        #pragma unroll
        for (int j = 0; j < 4; j++)
            acc[i][j] = (f32x4){0.f, 0.f, 0.f, 0.f};

    auto stage = [&](int buf, int k0) {
        #pragma unroll
        for (int i = 0; i < 2; i++) {
            const int rg = w * 2 + i;
            gl_lds16(&A [(size_t)(m0 + rg * 16 + ar) * lda + k0 + ac], &As[buf][rg * 512]);
            gl_lds16(&Bt[(size_t)(n0 + rg * 16 + ar) * ldb + k0 + ac], &Bs[buf][rg * 512]);
        }
    };
    auto compute = [&](int buf) {
        bf16x8 af[4], bfr[4];
        #pragma unroll
        for (int i = 0; i < 4; i++) {
            af[i]  = *(const bf16x8*)&As[buf][(wm * 64 + i * 16 + l15) * 32 + l16 * 8];
            bfr[i] = *(const bf16x8*)&Bs[buf][(wn * 64 + i * 16 + l15) * 32 + l16 * 8];
        }
        #pragma unroll
        for (int mi = 0; mi < 4; mi++)
            #pragma unroll
            for (int ni = 0; ni < 4; ni++)
                acc[mi][ni] = __builtin_amdgcn_mfma_f32_16x16x32_bf16(
                    af[mi], bfr[ni], acc[mi][ni], 0, 0, 0);
    };

    stage(0, 0);
    __syncthreads();
    int k0 = 0;
    for (; k0 + 32 < Klen; k0 += 32) {
        const int cur = (k0 >> 5) & 1;
        stage(cur ^ 1, k0 + 32);
        compute(cur);
        __syncthreads();
    }
    compute((k0 >> 5) & 1);

    if (CbT && blockIdx.z == 2) {
        // write V-projection directly transposed: vhT[(b*16+h)*64+d][s]
        #pragma unroll
        for (int ni = 0; ni < 4; ni++) {
            const int col = n0 + wn * 64 + ni * 16 + l15;   // h*64 + d
            const int hh = col >> 6, d = col & 63;
            #pragma unroll
            for (int mi = 0; mi < 4; mi++) {
                const int row = m0 + wm * 64 + mi * 16 + l16 * 4;  // b*2048 + s
                const int bb = row >> 11, s = row & 2047;
                ushort4 o;
                o.x = f2bf(acc[mi][ni][0]); o.y = f2bf(acc[mi][ni][1]);
                o.z = f2bf(acc[mi][ni][2]); o.w = f2bf(acc[mi][ni][3]);
                *(ushort4*)&CbT[((size_t)((bb * 16 + hh) * 64 + d)) * SEQ + s] = o;
            }
        }
        return;
    }

    #pragma unroll
    for (int ni = 0; ni < 4; ni++) {
        const int col = n0 + wn * 64 + ni * 16 + l15;
        const float bv = (ep && blockIdx.z == 0) ? bias[col] : 0.f;
        #pragma unroll
        for (int mi = 0; mi < 4; mi++) {
            #pragma unroll
            for (int r = 0; r < 4; r++) {
                const int row = m0 + wm * 64 + mi * 16 + l16 * 4 + r;
                float vv = acc[mi][ni][r] + bv;
                if (ep == 2) vv = fmaxf(vv, 0.f);
                if (Cf) Cf[cbase + (size_t)row * N + col] = vv;
                else    Cb[cbase + (size_t)row * N + col] = f2bf(vv);
            }
        }
    }
}

// ------------------------------------------------------------------
// Flash attention, S^T formulation. 8 waves / 128 q-rows per block.
// Round 14: round-12 2-barrier pipeline (in-loop mask loads) + Ps [128][64]
// XOR-granule swizzle. K,V double-buffered, prefetched one iter ahead.
// Ledger (per wave, issue order): entry outstanding = {V(t),K(t)};
//   issue mask(t)x4, V(t+1), K(t+1) -> 8; vmcnt(6) retires V(t),K(t);
//   compiler's mask-use wait (vmcnt<=2) keeps the prefetch pair in flight.
// PV follows softmax with only lgkmcnt(0) (Ps is wave-private).
// ------------------------------------------------------------------
__global__ __launch_bounds__(512) void attn_mfma(
    const unsigned short* __restrict__ qh, const unsigned short* __restrict__ kh,
    const unsigned short* __restrict__ vhT, const float* __restrict__ mask,
    unsigned short* __restrict__ z)
{
    __shared__ unsigned short Ks[2][64 * 64];   // swizzled [key][d], dbuf
    __shared__ unsigned short Vs[2][64 * 64];   // swizzled [d][key], dbuf
    __shared__ unsigned short Ps[128 * 64];     // [q][key] XOR-granule swizzled;
                                                // Q staging in prologue

    const int t = threadIdx.x, lane = t & 63, w = t >> 6;   // w 0..7
    const int bid = blockIdx.x;
    const int qt = bid >> 5, h = bid & 15, b = (bid >> 4) & 1;
    const int q0 = qt * 128, qr = w * 16;
    const int l15 = lane & 15, l16 = lane >> 4;

    const int lr = lane >> 3;
    const int gc = ((lane & 7) ^ lr) * 8;     // swizzled source chunk (shorts)

    const size_t qbase = (size_t)(b * SEQ + q0) * DM + h * 64;
    const size_t kbase = (size_t)(b * SEQ) * DM + h * 64;
    const size_t vbase = (size_t)((b * 16 + h) * 64) * SEQ;

    // prologue: Q (128 rows) -> Ps, K tile 0 -> Ks[0], V tile 0 -> Vs[0]
    #pragma unroll
    for (int i = 0; i < 2; i++) {
        const int rg = w * 2 + i;
        gl_lds16(&qh[qbase + (size_t)(rg * 8 + lr) * DM + gc], &Ps[rg * 512]);
    }
    gl_lds16(&kh [kbase + (size_t)(w * 8 + lr) * DM + gc],  &Ks[0][w * 512]);
    gl_lds16(&vhT[vbase + (size_t)(w * 8 + lr) * SEQ + gc], &Vs[0][w * 512]);
    __syncthreads();   // drains vmcnt(0): Q, K0, V0 resident

    const int sw0 = ((l16    ) ^ (l15 & 7)) * 8;
    const int sw1 = ((l16 + 4) ^ (l15 & 7)) * 8;
    const bf16x8 bQ0 = *(const bf16x8*)&Ps[(qr + l15) * 64 + sw0];
    const bf16x8 bQ1 = *(const bf16x8*)&Ps[(qr + l15) * 64 + sw1];
    __syncthreads();   // everyone consumed Q; Ps free for P

    // P-write swizzled offset: granule (ki*2 + (l16>>1)) ^ (l15&7), half l16&1
    const int pw_half = (l16 & 1) * 4;
    const int pw_x7   = l15 & 7;

    const float* mrow = mask + (size_t)(q0 + qr + l15) * SEQ;

    float m_i = -1e30f, l_i = 0.f;
    f32x4 o4[4];
    #pragma unroll
    for (int mi = 0; mi < 4; mi++) o4[mi] = (f32x4){0.f, 0.f, 0.f, 0.f};

    for (int kt = 0; kt < SEQ / 64; kt++) {
        const int k0 = kt * 64;
        const int kn = ((kt + 1) & (SEQ / 64 - 1)) * 64;   // wrap: last iter redundant
        const int cur = kt & 1, nxt = cur ^ 1;

        // (A) top barrier: all waves done with Ks[nxt]/Vs[nxt] from t-1.
        __builtin_amdgcn_s_barrier();

        float4 mv[4];
        #pragma unroll
        for (int ki = 0; ki < 4; ki++)
            mv[ki] = *(const float4*)&mrow[k0 + ki * 16 + l16 * 4];
        __builtin_amdgcn_sched_barrier(0);   // mask issued before prefetch pair

        gl_lds16(&vhT[vbase + (size_t)(w * 8 + lr) * SEQ + kn + gc], &Vs[nxt][w * 512]);
        gl_lds16(&kh [kbase + (size_t)(kn + w * 8 + lr) * DM + gc],  &Ks[nxt][w * 512]);

        // retire V(t),K(t) (oldest 2); mask4 + V/K prefetch stay in flight
        asm volatile("s_waitcnt vmcnt(6)" ::: "memory");
        __builtin_amdgcn_s_barrier();        // (B) tile t fully staged by all waves
        __builtin_amdgcn_sched_barrier(0);

        // S^T = K . Q^T : row=key, col=q
        f32x4 s4[4];
        __builtin_amdgcn_s_setprio(1);
        #pragma unroll
        for (int ki = 0; ki < 4; ki++) {
            const int r = ki * 16 + l15;
            const bf16x8 aK0 = *(const bf16x8*)&Ks[cur][r * 64 + sw0];
            const bf16x8 aK1 = *(const bf16x8*)&Ks[cur][r * 64 + sw1];
            f32x4 a0 = (f32x4){0.f, 0.f, 0.f, 0.f};
            a0 = __builtin_amdgcn_mfma_f32_16x16x32_bf16(aK0, bQ0, a0, 0, 0, 0);
            s4[ki] = __builtin_amdgcn_mfma_f32_16x16x32_bf16(aK1, bQ1, a0, 0, 0, 0);
        }
        __builtin_amdgcn_s_setprio(0);

        float sv[16];
        #pragma unroll
        for (int ki = 0; ki < 4; ki++) {
            sv[ki * 4 + 0] = s4[ki][0] * 0.125f + mv[ki].x;
            sv[ki * 4 + 1] = s4[ki][1] * 0.125f + mv[ki].y;
            sv[ki * 4 + 2] = s4[ki][2] * 0.125f + mv[ki].z;
            sv[ki * 4 + 3] = s4[ki][3] * 0.125f + mv[ki].w;
        }

        float rm = fmaxf(sv[0], sv[1]);
        #pragma unroll
        for (int i = 2; i < 16; i += 2) rm = fmaxf(fmaxf(rm, sv[i]), sv[i + 1]);
        rm = fmaxf(rm, __shfl_xor(rm, 16));
        rm = fmaxf(rm, __shfl_xor(rm, 32));

        const bool skip = __all(rm <= m_i + 8.f);
        float mnew = m_i, alpha = 1.f;
        if (!skip) { mnew = fmaxf(m_i, rm); alpha = __expf(m_i - mnew); }

        float ps = 0.f;
        #pragma unroll
        for (int ki = 0; ki < 4; ki++) {
            const float p0 = __expf(sv[ki * 4 + 0] - mnew);
            const float p1 = __expf(sv[ki * 4 + 1] - mnew);
            const float p2 = __expf(sv[ki * 4 + 2] - mnew);
            const float p3 = __expf(sv[ki * 4 + 3] - mnew);
            ps += (p0 + p1) + (p2 + p3);
            uint2 pk;
            pk.x = cvt_pk_bf16(p0, p1);
            pk.y = cvt_pk_bf16(p2, p3);
            // swizzled P write: granule (ki*2+(l16>>1)) ^ (l15&7), half l16&1
            *(uint2*)&Ps[(qr + l15) * 64 +
                         (((ki * 2 + (l16 >> 1)) ^ pw_x7) * 8 + pw_half)] = pk;
        }
        ps += __shfl_xor(ps, 16);
        ps += __shfl_xor(ps, 32);
        if (!skip) {
            m_i = mnew;
            l_i = l_i * alpha + ps;
            #pragma unroll
            for (int mi = 0; mi < 4; mi++)
                #pragma unroll
                for (int r = 0; r < 4; r++) o4[mi][r] *= alpha;
        } else {
            l_i += ps;
        }

        // Ps wave-private: own ds_writes just need to land before own ds_reads.
        asm volatile("s_waitcnt lgkmcnt(0)" ::: "memory");
        __builtin_amdgcn_sched_barrier(0);

        const bf16x8 bP0 = *(const bf16x8*)&Ps[(qr + l15) * 64 + sw0];
        const bf16x8 bP1 = *(const bf16x8*)&Ps[(qr + l15) * 64 + sw1];
        __builtin_amdgcn_s_setprio(1);
        #pragma unroll
        for (int mi = 0; mi < 4; mi++) {
            const int r = mi * 16 + l15;
            const bf16x8 aV0 = *(const bf16x8*)&Vs[cur][r * 64 + sw0];
            const bf16x8 aV1 = *(const bf16x8*)&Vs[cur][r * 64 + sw1];
            o4[mi] = __builtin_amdgcn_mfma_f32_16x16x32_bf16(aV0, bP0, o4[mi], 0, 0, 0);
            o4[mi] = __builtin_amdgcn_mfma_f32_16x16x32_bf16(aV1, bP1, o4[mi], 0, 0, 0);
        }
        __builtin_amdgcn_s_setprio(0);
    }

    asm volatile("s_waitcnt vmcnt(0)" ::: "memory");

    const float inv = 1.f / l_i;
    #pragma unroll
    for (int mi = 0; mi < 4; mi++) {
        const float a0 = o4[mi][0] * inv, a1 = o4[mi][1] * inv;
        const float a2 = o4[mi][2] * inv, a3 = o4[mi][3] * inv;
        uint2 ov;
        ov.x = cvt_pk_bf16(a0, a1);
        ov.y = cvt_pk_bf16(a2, a3);
        *(uint2*)&z[(size_t)(b * SEQ + q0 + qr + l15) * DM + h * 64 + mi * 16 + l16 * 4] = ov;
    }
}

// ------------------------------------------------------------------
// prep: one launch for all input prep. grid (64,16,9).
// ------------------------------------------------------------------
__global__ __launch_bounds__(256) void prep(
    const float* __restrict__ q, const float* __restrict__ k, const float* __restrict__ v,
    unsigned short* __restrict__ qb,
    const float* __restrict__ Wq, const float* __restrict__ Wk,
    const float* __restrict__ Wv, const float* __restrict__ Wd,
    const float* __restrict__ W1, const float* __restrict__ W2,
    unsigned short* __restrict__ Wqt, unsigned short* __restrict__ Wdt,
    unsigned short* __restrict__ W1t, unsigned short* __restrict__ W2t)
{
    const int z = blockIdx.z, t = threadIdx.x;
    const int flat = blockIdx.y * 64 + blockIdx.x;

    if (z < 3) {
        const float* src = z == 0 ? q : (z == 1 ? k : v);
        unsigned short* dst = qb + (size_t)z * ((size_t)SEQ * 2 * DM);
        const size_t base = (size_t)flat * 4096 + t * 4;
        #pragma unroll
        for (int i = 0; i < 4; i++) {
            const float4 w4 = *(const float4*)&src[base + i * 1024];
            ushort4 o; o.x = f2bf(w4.x); o.y = f2bf(w4.y); o.z = f2bf(w4.z); o.w = f2bf(w4.w);
            *(ushort4*)&dst[base + i * 1024] = o;
        }
        return;
    }

    __shared__ float ts[64][65];
    const float* W; unsigned short* Wt; int K, N, n0, k0;
    if (z < 7) {
        if (flat >= 256) return;
        W  = z == 3 ? Wq : z == 4 ? Wk : (z == 5 ? Wv : Wd);
        Wt = z == 3 ? Wqt : z == 4 ? Wqt + 1024 * 1024
           : z == 5 ? Wqt + 2 * 1024 * 1024 : Wdt;
        K = 1024; N = 1024;
        n0 = (flat & 15) * 64; k0 = (flat >> 4) * 64;
    } else if (z == 7) {
        W = W1; Wt = W1t; K = 1024; N = 4096;
        n0 = blockIdx.x * 64; k0 = blockIdx.y * 64;
    } else {
        W = W2; Wt = W2t; K = 4096; N = 1024;
        n0 = (flat & 15) * 64; k0 = (flat >> 4) * 64;
    }

    const int r = t >> 4, c4 = (t & 15) * 4;
    #pragma unroll
    for (int i = 0; i < 4; i++) {
        const float4 v4 = *(const float4*)&W[(size_t)(k0 + r + i * 16) * N + n0 + c4];
        ts[r + i * 16][c4 + 0] = v4.x; ts[r + i * 16][c4 + 1] = v4.y;
        ts[r + i * 16][c4 + 2] = v4.z; ts[r + i * 16][c4 + 3] = v4.w;
    }
    __syncthreads();
    #pragma unroll
    for (int i = 0; i < 4; i++) {
        const int n = r + i * 16;
        ushort4 o;
        o.x = f2bf(ts[c4 + 0][n]); o.y = f2bf(ts[c4 + 1][n]);
        o.z = f2bf(ts[c4 + 2][n]); o.w = f2bf(ts[c4 + 3][n]);
        *(ushort4*)&Wt[(size_t)(n0 + n) * K + k0 + c4] = o;
    }
}

// ------------------------------------------------------------------
// LN + residual, float4-vectorized; up to 4 partial inputs (nullable).
// mode 0: out = LN(sum)*g+be + r (+bf16 copy) ; mode 1: out = LN(sum+r)*g+be
// ------------------------------------------------------------------
__global__ __launch_bounds__(256) void ln_res(
    const float* __restrict__ a, const float* __restrict__ a2,
    const float* __restrict__ a3, const float* __restrict__ a4,
    const float* __restrict__ r,
    const float* __restrict__ g, const float* __restrict__ be,
    float* __restrict__ out, unsigned short* __restrict__ outb, int mode)
{
    __shared__ float redls[8];
    const int row = blockIdx.x, t = threadIdx.x;
    const size_t base = (size_t)row * DM;
    const int c = t * 4;

    float4 va = *(const float4*)&a[base + c];
    if (a2) { const float4 v2 = *(const float4*)&a2[base + c];
              va.x += v2.x; va.y += v2.y; va.z += v2.z; va.w += v2.w; }
    if (a3) { const float4 v3 = *(const float4*)&a3[base + c];
              va.x += v3.x; va.y += v3.y; va.z += v3.z; va.w += v3.w; }
    if (a4) { const float4 v4 = *(const float4*)&a4[base + c];
              va.x += v4.x; va.y += v4.y; va.z += v4.z; va.w += v4.w; }
    float4 vr;
    if (mode == 1) { vr = *(const float4*)&r[base + c];
                     va.x += vr.x; va.y += vr.y; va.z += vr.z; va.w += vr.w; }

    float s  = (va.x + va.y) + (va.z + va.w);
    float sq = (va.x * va.x + va.y * va.y) + (va.z * va.z + va.w * va.w);
    #pragma unroll
    for (int off = 32; off > 0; off >>= 1) { s += __shfl_down(s, off); sq += __shfl_down(sq, off); }
    if ((t & 63) == 0) { redls[t >> 6] = s; redls[4 + (t >> 6)] = sq; }
    __syncthreads();
    s  = redls[0] + redls[1] + redls[2] + redls[3];
    sq = redls[4] + redls[5] + redls[6] + redls[7];

    const float mu  = s * (1.f / 1024.f);
    const float var = sq * (1.f / 1024.f) - mu * mu;
    const float rs  = rsqrtf(var + LNEPS);

    const float4 vg = *(const float4*)&g[c];
    const float4 vb = *(const float4*)&be[c];
    float4 y;
    y.x = (va.x - mu) * rs * vg.x + vb.x;
    y.y = (va.y - mu) * rs * vg.y + vb.y;
    y.z = (va.z - mu) * rs * vg.z + vb.z;
    y.w = (va.w - mu) * rs * vg.w + vb.w;
    if (mode == 0) {
        vr = *(const float4*)&r[base + c];
        y.x += vr.x; y.y += vr.y; y.z += vr.z; y.w += vr.w;
    }
    *(float4*)&out[base + c] = y;
    if (outb) {
        ushort4 o;
        o.x = f2bf(y.x); o.y = f2bf(y.y); o.z = f2bf(y.z); o.w = f2bf(y.w);
        *(ushort4*)&outb[base + c] = o;
    }
}

// ------------------------------------------------------------------
extern "C" void kernel_launch(void* const* d_in, const int* in_sizes, int n_in,
                              void* d_out, int out_size, void* d_ws, size_t ws_size,
                              hipStream_t stream)
{
    const float* q    = (const float*)d_in[0];
    const float* k    = (const float*)d_in[1];
    const float* v    = (const float*)d_in[2];
    const float* mask = (const float*)d_in[4];
    const float* Wq   = (const float*)d_in[5];
    const float* Wk   = (const float*)d_in[6];
    const float* Wv   = (const float*)d_in[7];
    const float* Wd   = (const float*)d_in[8];
    const float* W1   = (const float*)d_in[9];
    const float* b1   = (const float*)d_in[10];
    const float* W2   = (const float*)d_in[11];
    const float* b2   = (const float*)d_in[12];
    const float* g1   = (const float*)d_in[13];
    const float* be1  = (const float*)d_in[14];
    const float* g2   = (const float*)d_in[15];
    const float* be2  = (const float*)d_in[16];
    float* out = (float*)d_out;

    char* WS = (char*)d_ws;
    const size_t MiB = 1u << 20;
    const size_t ND  = (size_t)4096 * 1024;

    unsigned short* qb  = (unsigned short*)(WS + 0);          // 24 MiB qb|kb|vb
    unsigned short* zb  = (unsigned short*)(WS + 8 * MiB);    //  8 MiB (reuse)
    unsigned short* xb  = (unsigned short*)(WS + 16 * MiB);   //  8 MiB (reuse)
    unsigned short* Wqt = (unsigned short*)(WS + 24 * MiB);   //  6 MiB WqT|WkT|WvT
    unsigned short* Wdt = (unsigned short*)(WS + 30 * MiB);   //  2 MiB
    unsigned short* W1t = (unsigned short*)(WS + 32 * MiB);   //  8 MiB
    unsigned short* W2t = (unsigned short*)(WS + 40 * MiB);   //  8 MiB
    unsigned short* qh  = (unsigned short*)(WS + 48 * MiB);   // 16 MiB qh|kh
    unsigned short* vhT = (unsigned short*)(WS + 64 * MiB);   //  8 MiB (direct)
    float*          zd0 = (float*)(WS + 48 * MiB);            // 16 MiB (reuse qh|kh)
    float*          zd1 = (float*)(WS + 64 * MiB);            // 16 MiB (reuse vhT+)
    float*          x   = (float*)(WS + 80 * MiB);            // 16 MiB
    unsigned short* h1  = (unsigned short*)(WS + 96 * MiB);   // 32 MiB
    // FFN2 split-K4 partials, slots {0,1,3,4} x 16 MiB (slot 2 = live W1t/W2t)
    float*          y0  = (float*)(WS + 0);
    float*          y1  = (float*)(WS + 16 * MiB);
    float*          y2  = (float*)(WS + 48 * MiB);
    float*          y3  = (float*)(WS + 64 * MiB);

    unsigned short* kh = qh + ND;

    const dim3 blk(256);

    prep<<<dim3(64, 16, 9), blk, 0, stream>>>(q, k, v, qb, Wq, Wk, Wv, Wd, W1, W2,
                                              Wqt, Wdt, W1t, W2t);

    // QKV projections via 2-phase gemm_bf16 (768 blocks; z==2 writes vhT)
    gemm_bf16<<<dim3(256, 1, 3), blk, 0, stream>>>(qb, Wqt, nullptr, qh, vhT,
        4096, 1024, 1024, 1024, 1024, ND, (size_t)1024 * 1024, ND, nullptr, 0, 3);

    attn_mfma<<<dim3(512), dim3(512), 0, stream>>>(qh, kh, vhT, mask, zb);

    // out-proj, split-K x2 -> zd0/zd1
    gemm_bf16<<<dim3(256, 1, 2), blk, 0, stream>>>(zb, Wdt, zd0, nullptr, nullptr,
        4096, 1024, 512, 1024, 1024, 512, 512, ND, nullptr, 0, 3);

    // LN1: x = LN(zd0+zd1) + q
    ln_res<<<dim3(4096), blk, 0, stream>>>(zd0, zd1, nullptr, nullptr, q,
                                           g1, be1, x, xb, 0);

    // FFN1 via gemm256 (grid 256 = 1 block/CU), bf16 out + bias + relu
    gemm256<<<dim3(256, 1, 1), dim3(512), 0, stream>>>(xb, W1t, h1, nullptr,
        4096, 1024, 1024, 1024, 0, 0, 0, 0, b1, 2, 4);

    // FFN2 via gemm256 split-K4 (grid 64x4 = 256 wg = 1 block/CU), fp32
    // partials to slots {0,1,3,4} x 16 MiB; bias b2 on z==0
    gemm256<<<dim3(64, 1, 4), dim3(512), 0, stream>>>(h1, W2t, nullptr, (float*)WS,
        1024, 1024, 4096, 4096, 1024, 1024, (size_t)4 * 1024 * 1024, 1, b2, 1, 2);

    // LN2: out = LN(y0+y1+y2+y3+x)
    ln_res<<<dim3(4096), blk, 0, stream>>>(y0, y1, y2, y3, x, g2, be2, out, nullptr, 1);
}